// Round 4
// baseline (309.046 us; speedup 1.0000x reference)
//
#include <hip/hip_runtime.h>
#include <hip/hip_bf16.h>

#define NHD 8
#define HD  32
#define C_  256
#define TD_ 512
#define S_  256
#define N_  32768   // D*H*W
#define B_  2

typedef short bf16x8 __attribute__((ext_vector_type(8)));
typedef short bf16x4 __attribute__((ext_vector_type(4)));
typedef float f32x4  __attribute__((ext_vector_type(4)));

#define MFMA16(a,b,c) __builtin_amdgcn_mfma_f32_16x16x32_bf16(a,b,c,0,0,0)

__device__ __forceinline__ short f2bf(float f){
    __hip_bfloat16 h = __float2bfloat16(f);
    return *reinterpret_cast<short*>(&h);
}

// ---------------------------------------------------------------------------
// async global->LDS staging (16B/lane, linear dest; verified R1/R2).
// ---------------------------------------------------------------------------
typedef __attribute__((address_space(3))) unsigned int lds_u32;
typedef const __attribute__((address_space(1))) unsigned int glb_u32;

__device__ __forceinline__ void async_cp16(const void* g, void* l){
    __builtin_amdgcn_global_load_lds(
        (glb_u32*)(unsigned long long)g,
        (lds_u32*)(unsigned int)(unsigned long long)l,
        16, 0, 0);
}

// stage one 16 KB verbatim tile (8192 shorts): 4 rounds x 256 thr x 16B
__device__ __forceinline__ void stage_tile(const short* __restrict__ g, short* l, int tid){
    const int wvb = tid & 192;            // (tid>>6)<<6 : wave-uniform
#pragma unroll
    for (int r = 0; r < 4; ++r)
        async_cp16(g + (r * 256 + tid) * 8, l + (r * 256 + wvb) * 8);
}

// ---------------------------------------------------------------------------
// text1: token-tiled GEMM for k/v/m1 (+gelu). 128 blocks x 4 tokens.
// Token rows in LDS; thread owns col tid of all 3 matrices -> 12 FMA per
// 3 weight loads. Accumulation: f32, strictly ascending j, init = bias ->
// bit-identical to the verified per-token path.
// Blocks 128..191: prep_wf fold (body verbatim from verified prep_wf).
// ---------------------------------------------------------------------------
#define T1_LD(K,V,M,j0) _Pragma("unroll") for(int i=0;i<8;++i){ \
    K[i]=kp[(j0+i)*C_]; V[i]=vp[(j0+i)*C_]; M[i]=mp[(j0+i)*C_]; }
#define T1_FM(K,V,M,j0) _Pragma("unroll") for(int i=0;i<8;++i){ \
    _Pragma("unroll") for(int m=0;m<4;++m){ float tv=t_s[m*TD_+j0+i]; \
        accK[m]+=tv*K[i]; accV[m]+=tv*V[i]; accH[m]+=tv*M[i]; } }

__global__ __launch_bounds__(256) void text1(
    const float* __restrict__ text,
    const float* __restrict__ k_w, const float* __restrict__ k_b,
    const float* __restrict__ v_w, const float* __restrict__ v_b,
    const float* __restrict__ m1_w, const float* __restrict__ m1_b,
    const float* __restrict__ qw, const float* __restrict__ ow,
    float* __restrict__ kraw, float* __restrict__ vraw, float* __restrict__ hgb,
    short* __restrict__ wqf, short* __restrict__ wof)
{
    const int tid = threadIdx.x;

    if (blockIdx.x >= 128) {
        // ---- prep_wf fold (verbatim, verified) ----
        int gid = (blockIdx.x - 128) * 256 + tid;   // 0..16383
        int m = gid >> 13;
        int rest = gid & 8191;
        const float* src = m ? ow : qw;
        short* dst = m ? wof : wqf;
        int lane = rest & 63;
        int l15 = lane & 15, qd = lane >> 4;
        int cbase, co;
        if (m == 0) { int nt = rest >> 9, cc = (rest >> 6) & 7; cbase = cc * 32 + qd * 8; co = nt * 16 + l15; }
        else        { int hm = rest >> 6; cbase = (hm >> 4) * 32 + qd * 8; co = (hm & 15) * 16 + l15; }
        bf16x8 r;
#pragma unroll
        for (int j = 0; j < 8; ++j) r[j] = f2bf(src[(size_t)(cbase + j) * 256 + co]);
        *(bf16x8*)&dst[(size_t)rest * 8] = r;
        return;
    }

    __shared__ float t_s[4 * TD_];    // 8 KB
    const int tok0 = blockIdx.x * 4;
#pragma unroll
    for (int i = 0; i < 2; ++i) {
        int idx = i * 256 + tid;      // 0..511 float4 units
        *(float4*)&t_s[idx * 4] = *(const float4*)&text[(size_t)tok0 * TD_ + idx * 4];
    }
    __syncthreads();

    float accK[4], accV[4], accH[4];
#pragma unroll
    for (int m = 0; m < 4; ++m) { accK[m] = k_b[tid]; accV[m] = v_b[tid]; accH[m] = m1_b[tid]; }
    const float* kp = k_w + tid;
    const float* vp = v_w + tid;
    const float* mp = m1_w + tid;

    {
        float ka[8], va[8], ma[8], kb2[8], vb2[8], mb2[8];
        T1_LD(ka, va, ma, 0);
#pragma unroll 1
        for (int j0 = 0; j0 < TD_; j0 += 16) {
            T1_LD(kb2, vb2, mb2, j0 + 8);
            T1_FM(ka, va, ma, j0);
            if (j0 + 16 < TD_) { T1_LD(ka, va, ma, j0 + 16); }
            T1_FM(kb2, vb2, mb2, j0 + 8);
        }
    }

#pragma unroll
    for (int m = 0; m < 4; ++m) {
        kraw[(size_t)(tok0 + m) * C_ + tid] = accK[m];
        vraw[(size_t)(tok0 + m) * C_ + tid] = accV[m];
        float hv = accH[m];
        hgb[(size_t)(tok0 + m) * C_ + tid] = 0.5f * hv * (1.0f + erff(hv * 0.70710678118654752f));
    }
}

// ---------------------------------------------------------------------------
// text2: phase GEMM + RoPE finalize + fragment-ordered kf/vf writes.
// 64 blocks x 8 tokens. Phase accumulation ascending j, init m2_b ->
// bit-identical to verified path; kf/vf index formulas verbatim.
// ---------------------------------------------------------------------------
#define T2_LD(G, j0) _Pragma("unroll") for (int i = 0; i < 8; ++i) G[i] = m2p[(j0 + i) * C_];
#define T2_FM(G, j0) _Pragma("unroll") for (int i = 0; i < 8; ++i) { \
    _Pragma("unroll") for (int m = 0; m < 8; ++m) accP[m] += h_s[m * C_ + j0 + i] * G[i]; }

__global__ __launch_bounds__(256) void text2(
    const float* __restrict__ m2_w, const float* __restrict__ m2_b,
    const float* __restrict__ kraw, const float* __restrict__ vraw,
    const float* __restrict__ hgb,
    short* __restrict__ kf, short* __restrict__ vf)
{
    __shared__ float h_s[8 * C_];     // 8 KB
    const int tid = threadIdx.x;
    const int tok0 = blockIdx.x * 8;
#pragma unroll
    for (int i = 0; i < 2; ++i) {
        int idx = i * 256 + tid;
        *(float4*)&h_s[idx * 4] = *(const float4*)&hgb[(size_t)tok0 * C_ + idx * 4];
    }
    __syncthreads();

    float accP[8];
#pragma unroll
    for (int m = 0; m < 8; ++m) accP[m] = m2_b[tid];
    const float* m2p = m2_w + tid;
    {
        float ga[8], gb2[8];
        T2_LD(ga, 0);
#pragma unroll 1
        for (int j0 = 0; j0 < C_; j0 += 16) {
            T2_LD(gb2, j0 + 8);
            T2_FM(ga, j0);
            if (j0 + 16 < C_) { T2_LD(ga, j0 + 16); }
            T2_FM(gb2, j0 + 8);
        }
    }

    const int t = tid & (HD - 1);
    const int nh = tid >> 5;
#pragma unroll
    for (int m = 0; m < 8; ++m) {
        int token = tok0 + m;
        int b = token >> 8, s = token & (S_ - 1);
        int bh = b * NHD + nh;
        float kv = kraw[(size_t)token * C_ + tid];
        float vv = vraw[(size_t)token * C_ + tid];
        float partner = (t < 16) ? -kraw[(size_t)token * C_ + tid + 16]
                                 :  kraw[(size_t)token * C_ + tid - 16];
        float ph = accP[m];
        float kr = kv * cosf(ph) + partner * sinf(ph);
        kf[(((size_t)bh * 16 + (s >> 4)) * 64 + (t >> 3) * 16 + (s & 15)) * 8 + (t & 7)] = f2bf(kr);
        vf[((((size_t)bh * 8 + (s >> 5)) * 2 + (t >> 4)) * 64 + ((s >> 3) & 3) * 16 + (t & 15)) * 8 + (s & 7)] = f2bf(vv);
    }
}

// 3D rope freq (verified R3/R4/R6)
__device__ __forceinline__ float freq3d(int t, int n){
    int d = n >> 10, h = (n >> 5) & 31, w = n & 31;
    float pos, ex;
    if (t < 10)      { pos = (float)d; ex = (float)(2 * (t % 5)) * 0.1f; }
    else if (t < 20) { pos = (float)h; ex = (float)(2 * ((t - 10) % 5)) * 0.1f; }
    else             { pos = (float)w; ex = (float)(2 * ((t - 20) % 6)) * (1.0f / 12.0f); }
    return pos * expf(-ex * 9.210340371976184f);
}

// ---------------------------------------------------------------------------
// FUSED: qproj + RoPE + attention + oproj (verified R2 structure).
// R4: A-operand af[8] loaded DIRECTLY from fv with per-lane scalar loads
// (64B coalesced per 16-lane group) — no LDS transpose, no extra barriers.
// af[cc][j] = bf16(fv[b][cc*32+qd*8+j][n0+wv*16+l15])  (== prep_fvtf semantics).
// wq tile-0 DMA issued first so the ring's opening barrier drains both.
// ---------------------------------------------------------------------------
__global__ __launch_bounds__(256, 4) void fused_visual(
    const float* __restrict__ fv, const short* __restrict__ wqf,
    const float* __restrict__ q_b, const short* __restrict__ kf,
    const short* __restrict__ vf, const short* __restrict__ wof,
    const float* __restrict__ o_b, float* __restrict__ out)
{
    __shared__ __align__(16) short Stg[16384];      // 2 slots x 8192 shorts (16KB each)
    __shared__ __align__(16) short Pb[4 * 16 * 64]; // 8 KB (P; Ot aliases)
    const int tid = threadIdx.x;
    const int lane = tid & 63;
    const int l15 = tid & 15, qd = (tid >> 4) & 3, wv = tid >> 6;
    const int n0 = blockIdx.x * 64;
    const int b = blockIdx.y;
    const f32x4 z4 = {0.f, 0.f, 0.f, 0.f};
    const float scale = 0.17677669529663687f;  // 32^-0.5, folded into Q

    short* slot0 = Stg;
    short* slot1 = Stg + 8192;

    // wq tile 0 DMA first (drained at the ring's first barrier)
    stage_tile(wqf, slot0, tid);

    // ---------------- A-operand: direct loads ----------------
    bf16x8 af[8];
    {
        const float* fbase = fv + ((size_t)b * C_) * N_ + n0 + wv * 16 + l15;
#pragma unroll
        for (int cc = 0; cc < 8; ++cc) {
            float tmp[8];
#pragma unroll
            for (int j = 0; j < 8; ++j)
                tmp[j] = fbase[(size_t)(cc * 32 + qd * 8 + j) * N_];
#pragma unroll
            for (int j = 0; j < 8; ++j) af[cc][j] = f2bf(tmp[j]);
        }
    }

    // ---------------- qproj (staged-ring wq; verified R2) ----------------
    f32x4 acc[16];
#pragma unroll
    for (int i = 0; i < 16; ++i) acc[i] = z4;

#pragma unroll
    for (int ntp = 0; ntp < 8; ++ntp) {
        __syncthreads();             // wq tile ntp landed
        if (ntp < 7) stage_tile(wqf + (ntp + 1) * 8192, (ntp & 1) ? slot0 : slot1, tid);
        const short* sb = (ntp & 1) ? slot1 : slot0;
#pragma unroll
        for (int cc = 0; cc < 8; ++cc)
#pragma unroll
            for (int ntl = 0; ntl < 2; ++ntl) {
                bf16x8 bq = *(const bf16x8*)&sb[((ntl * 8 + cc) * 64 + lane) * 8];
                acc[ntp * 2 + ntl] = MFMA16(af[cc], bq, acc[ntp * 2 + ntl]);
            }
    }
    __syncthreads();   // all waves done with last wq tile; Stg reusable as scratch

    // ---------------- RoPE -> wave-private scratch, aqh[] to regs ----------
    short* Qsc = Stg + wv * 4096;    // 8KB per wave (16 rows x 256 shorts)
#pragma unroll
    for (int r = 0; r < 4; ++r) {
        int lr = qd * 4 + r;                  // local row
        int n = n0 + wv * 16 + lr;
        int key = lr & 7;
        float f1 = freq3d(l15, n), f2 = freq3d(l15 + 16, n);
        float c1 = cosf(f1), s1 = sinf(f1), c2 = cosf(f2), s2 = sinf(f2);
#pragma unroll
        for (int hh = 0; hh < 8; ++hh) {
            float x1 = acc[2 * hh][r]     + q_b[hh * 32 + l15];
            float x2 = acc[2 * hh + 1][r] + q_b[hh * 32 + 16 + l15];
            int cb1 = (hh * 4 + (l15 >> 3)) ^ key;
            int cb2 = (hh * 4 + 2 + (l15 >> 3)) ^ key;
            Qsc[lr * 256 + cb1 * 8 + (l15 & 7)] = f2bf((x1 * c1 - x2 * s1) * scale);
            Qsc[lr * 256 + cb2 * 8 + (l15 & 7)] = f2bf((x2 * c2 + x1 * s2) * scale);
        }
    }
    // per-wave in-order DS: own writes visible to own reads without barrier
    bf16x8 aqh[8];
#pragma unroll
    for (int h = 0; h < 8; ++h)
        aqh[h] = *(const bf16x8*)&Qsc[l15 * 256 + ((h * 4 + qd) ^ (l15 & 7)) * 8];

    __syncthreads();   // all waves done with scratch -> slot0 free for K(0)
    stage_tile(kf + (size_t)(b * NHD) * 8192, slot0, tid);

    // ---------------- attention + accumulated oproj ----------------
    f32x4 acc_co[16];
#pragma unroll
    for (int i = 0; i < 16; ++i) acc_co[i] = z4;
    short* Pw = Pb + wv * 16 * 64;
    short* Ow = Pw;   // alias (per-wave in-order DS makes this safe)

#pragma unroll
    for (int h = 0; h < 8; ++h) {
        const int bh = b * NHD + h;
        __syncthreads();                                   // K(h) landed
        stage_tile(wof + (size_t)h * 8192, slot1, tid);    // WO(h): consumed after mid barrier

        const short* vbase = vf + (size_t)bh * 8192;

        float tsum[4] = {0.f, 0.f, 0.f, 0.f};
        f32x4 o0 = z4, o1 = z4;

#pragma unroll
        for (int qt = 0; qt < 4; ++qt) {
            f32x4 sc[4];
#pragma unroll
            for (int s4 = 0; s4 < 4; ++s4) {
                bf16x8 bk = *(const bf16x8*)&slot0[(qt * 4 + s4) * 512 + lane * 8];
                sc[s4] = MFMA16(aqh[h], bk, z4);
            }
#pragma unroll
            for (int s4 = 0; s4 < 4; ++s4)
#pragma unroll
                for (int r = 0; r < 4; ++r) {
                    sc[s4][r] = __expf(sc[s4][r]);
                    tsum[r] += sc[s4][r];
                }
#pragma unroll
            for (int s4 = 0; s4 < 4; ++s4)
#pragma unroll
                for (int r = 0; r < 4; ++r) {
                    int row = qd * 4 + r;
                    Pw[row * 64 + ((s4 * 2 + (l15 >> 3)) ^ (row & 7)) * 8 + (l15 & 7)] = f2bf(sc[s4][r]);
                }
#pragma unroll
            for (int ktl = 0; ktl < 2; ++ktl) {
                bf16x8 pa = *(const bf16x8*)&Pw[l15 * 64 + ((ktl * 4 + qd) ^ (l15 & 7)) * 8];
                int kt = qt * 2 + ktl;
                bf16x8 v0 = *(const bf16x8*)&vbase[(kt * 2 + 0) * 512 + lane * 8];
                bf16x8 v1 = *(const bf16x8*)&vbase[(kt * 2 + 1) * 512 + lane * 8];
                o0 = MFMA16(pa, v0, o0);
                o1 = MFMA16(pa, v1, o1);
            }
        }
        float il[4];
#pragma unroll
        for (int r = 0; r < 4; ++r) {
            float t = tsum[r];
            t += __shfl_xor(t, 1); t += __shfl_xor(t, 2);
            t += __shfl_xor(t, 4); t += __shfl_xor(t, 8);
            il[r] = 1.f / t;
        }
        // O -> Ot (aliased in Pw), key = row&3
#pragma unroll
        for (int r = 0; r < 4; ++r) {
            int row = qd * 4 + r;
            int key = row & 3;
            Ow[row * 32 + (((l15 >> 3) ^ key) & 3) * 8 + (l15 & 7)]       = f2bf(o0[r] * il[r]);
            Ow[row * 32 + (((2 + (l15 >> 3)) ^ key) & 3) * 8 + (l15 & 7)] = f2bf(o1[r] * il[r]);
        }

        __syncthreads();   // WO(h) landed; all waves done reading K(h) -> slot0 free
        if (h < 7)
            stage_tile(kf + (size_t)(bh + 1) * 8192, slot0, tid);  // covered by oproj

        // oproj from slot1 (LDS); Ow is wave-private Pb, untouched by staging
        bf16x8 bo = *(const bf16x8*)&Ow[l15 * 32 + ((qd ^ (l15 & 3)) & 3) * 8];
#pragma unroll
        for (int mt = 0; mt < 16; ++mt) {
            bf16x8 ao = *(const bf16x8*)&slot1[mt * 512 + lane * 8];
            acc_co[mt] = MFMA16(ao, bo, acc_co[mt]);
        }
    }

    // ---------------- epilogue: rows = co, cols = n -> coalesced stores ----
#pragma unroll
    for (int mt = 0; mt < 16; ++mt)
#pragma unroll
        for (int r = 0; r < 4; ++r) {
            int co = mt * 16 + qd * 4 + r;
            out[(size_t)(b * C_ + co) * N_ + n0 + wv * 16 + l15] = acc_co[mt][r] + o_b[co];
        }
}

// ---------------------------------------------------------------------------
extern "C" void kernel_launch(void* const* d_in, const int* in_sizes, int n_in,
                              void* d_out, int out_size, void* d_ws, size_t ws_size,
                              hipStream_t stream) {
    (void)in_sizes; (void)n_in; (void)out_size; (void)ws_size;
    const float* fv   = (const float*)d_in[0];
    const float* text = (const float*)d_in[1];
    const float* q_w  = (const float*)d_in[2];
    const float* q_b  = (const float*)d_in[3];
    const float* k_w  = (const float*)d_in[4];
    const float* k_b  = (const float*)d_in[5];
    const float* v_w  = (const float*)d_in[6];
    const float* v_b  = (const float*)d_in[7];
    const float* o_w  = (const float*)d_in[8];
    const float* o_b  = (const float*)d_in[9];
    const float* m1_w = (const float*)d_in[10];
    const float* m1_b = (const float*)d_in[11];
    const float* m2_w = (const float*)d_in[12];
    const float* m2_b = (const float*)d_in[13];
    float* out = (float*)d_out;

    short* wsS  = (short*)d_ws;
    short* kf   = wsS;                      // 131072 shorts
    short* vf   = wsS + 131072;             // 131072
    short* wqf  = wsS + 262144;             // 65536
    short* wof  = wsS + 327680;             // 65536
    float* kraw = (float*)(wsS + 393216);   // 131072 floats
    float* vraw = kraw + 131072;            // 131072
    float* hgb  = kraw + 262144;            // 131072

    hipLaunchKernelGGL(text1, dim3(192), dim3(256), 0, stream,
                       text, k_w, k_b, v_w, v_b, m1_w, m1_b,
                       q_w, o_w, kraw, vraw, hgb, wqf, wof);
    hipLaunchKernelGGL(text2, dim3(64), dim3(256), 0, stream,
                       m2_w, m2_b, kraw, vraw, hgb, kf, vf);
    hipLaunchKernelGGL(fused_visual, dim3(512, 2), dim3(256), 0, stream,
                       fv, wqf, q_b, kf, vf, wof, o_b, out);
}

// Round 6
// 305.197 us; speedup vs baseline: 1.0126x; 1.0126x over previous
//
#include <hip/hip_runtime.h>
#include <hip/hip_bf16.h>

#define NHD 8
#define HD  32
#define C_  256
#define TD_ 512
#define S_  256
#define N_  32768   // D*H*W
#define B_  2

typedef short bf16x8 __attribute__((ext_vector_type(8)));
typedef short bf16x4 __attribute__((ext_vector_type(4)));
typedef float f32x4  __attribute__((ext_vector_type(4)));

#define MFMA16(a,b,c) __builtin_amdgcn_mfma_f32_16x16x32_bf16(a,b,c,0,0,0)

__device__ __forceinline__ short f2bf(float f){
    __hip_bfloat16 h = __float2bfloat16(f);
    return *reinterpret_cast<short*>(&h);
}

// ---------------------------------------------------------------------------
// async global->LDS staging (16B/lane, linear dest; verified R1/R2).
// ---------------------------------------------------------------------------
typedef __attribute__((address_space(3))) unsigned int lds_u32;
typedef const __attribute__((address_space(1))) unsigned int glb_u32;

__device__ __forceinline__ void async_cp16(const void* g, void* l){
    __builtin_amdgcn_global_load_lds(
        (glb_u32*)(unsigned long long)g,
        (lds_u32*)(unsigned int)(unsigned long long)l,
        16, 0, 0);
}

// stage one 16 KB verbatim tile (8192 shorts): 4 rounds x 256 thr x 16B
__device__ __forceinline__ void stage_tile(const short* __restrict__ g, short* l, int tid){
    const int wvb = tid & 192;            // (tid>>6)<<6 : wave-uniform
#pragma unroll
    for (int r = 0; r < 4; ++r)
        async_cp16(g + (r * 256 + tid) * 8, l + (r * 256 + wvb) * 8);
}

// ---------------------------------------------------------------------------
// text_all: k/v/m1 GEMM (+gelu) AND m2 phase GEMM AND RoPE finalize, one
// kernel. 128 GEMM blocks x 4 tokens (block holds full 256-dim h,k vectors
// in LDS -> m2 phase needs no global round-trip). Accumulation f32,
// strictly ascending j at every stage -> bit-identical to verified R4 path.
// Blocks 128..191: prep_wf fold (body verbatim, verified).
// ---------------------------------------------------------------------------
#define T1_LD(K,V,M,j0) _Pragma("unroll") for(int i=0;i<8;++i){ \
    K[i]=kp[(j0+i)*C_]; V[i]=vp[(j0+i)*C_]; M[i]=mp[(j0+i)*C_]; }
#define T1_FM(K,V,M,j0) _Pragma("unroll") for(int i=0;i<8;++i){ \
    _Pragma("unroll") for(int m=0;m<4;++m){ float tv=t_s[m*TD_+j0+i]; \
        accK[m]+=tv*K[i]; accV[m]+=tv*V[i]; accH[m]+=tv*M[i]; } }
#define T2_LD(G, j0) _Pragma("unroll") for (int i = 0; i < 8; ++i) G[i] = m2p[(j0 + i) * C_];
#define T2_FM(G, j0) _Pragma("unroll") for (int i = 0; i < 8; ++i) { \
    _Pragma("unroll") for (int m = 0; m < 4; ++m) accP[m] += h_s[m * C_ + j0 + i] * G[i]; }

__global__ __launch_bounds__(256) void text_all(
    const float* __restrict__ text,
    const float* __restrict__ k_w, const float* __restrict__ k_b,
    const float* __restrict__ v_w, const float* __restrict__ v_b,
    const float* __restrict__ m1_w, const float* __restrict__ m1_b,
    const float* __restrict__ m2_w, const float* __restrict__ m2_b,
    const float* __restrict__ qw, const float* __restrict__ ow,
    short* __restrict__ kf, short* __restrict__ vf,
    short* __restrict__ wqf, short* __restrict__ wof)
{
    const int tid = threadIdx.x;

    if (blockIdx.x >= 128) {
        // ---- prep_wf fold (verbatim, verified) ----
        int gid = (blockIdx.x - 128) * 256 + tid;   // 0..16383
        int m = gid >> 13;
        int rest = gid & 8191;
        const float* src = m ? ow : qw;
        short* dst = m ? wof : wqf;
        int lane = rest & 63;
        int l15 = lane & 15, qd = lane >> 4;
        int cbase, co;
        if (m == 0) { int nt = rest >> 9, cc = (rest >> 6) & 7; cbase = cc * 32 + qd * 8; co = nt * 16 + l15; }
        else        { int hm = rest >> 6; cbase = (hm >> 4) * 32 + qd * 8; co = (hm & 15) * 16 + l15; }
        bf16x8 r;
#pragma unroll
        for (int j = 0; j < 8; ++j) r[j] = f2bf(src[(size_t)(cbase + j) * 256 + co]);
        *(bf16x8*)&dst[(size_t)rest * 8] = r;
        return;
    }

    __shared__ float t_s[4 * TD_];    // 8 KB
    __shared__ float h_s[4 * C_];     // 4 KB
    __shared__ float k_s[4 * C_];     // 4 KB
    const int tok0 = blockIdx.x * 4;
#pragma unroll
    for (int i = 0; i < 2; ++i) {
        int idx = i * 256 + tid;      // 0..511 float4 units
        *(float4*)&t_s[idx * 4] = *(const float4*)&text[(size_t)tok0 * TD_ + idx * 4];
    }
    __syncthreads();

    float accK[4], accV[4], accH[4];
#pragma unroll
    for (int m = 0; m < 4; ++m) { accK[m] = k_b[tid]; accV[m] = v_b[tid]; accH[m] = m1_b[tid]; }
    const float* kp = k_w + tid;
    const float* vp = v_w + tid;
    const float* mp = m1_w + tid;

    {
        float ka[8], va[8], ma[8], kb2[8], vb2[8], mb2[8];
        T1_LD(ka, va, ma, 0);
#pragma unroll 1
        for (int j0 = 0; j0 < TD_; j0 += 16) {
            T1_LD(kb2, vb2, mb2, j0 + 8);
            T1_FM(ka, va, ma, j0);
            if (j0 + 16 < TD_) { T1_LD(ka, va, ma, j0 + 16); }
            T1_FM(kb2, vb2, mb2, j0 + 8);
        }
    }

#pragma unroll
    for (int m = 0; m < 4; ++m) {
        k_s[m * C_ + tid] = accK[m];
        float hv = accH[m];
        h_s[m * C_ + tid] = 0.5f * hv * (1.0f + erff(hv * 0.70710678118654752f));
    }
    __syncthreads();

    // ---- m2 phase GEMM (ascending j, init m2_b -> bit-identical) ----
    float accP[4];
#pragma unroll
    for (int m = 0; m < 4; ++m) accP[m] = m2_b[tid];
    const float* m2p = m2_w + tid;
    {
        float ga[8], gb2[8];
        T2_LD(ga, 0);
#pragma unroll 1
        for (int j0 = 0; j0 < C_; j0 += 16) {
            T2_LD(gb2, j0 + 8);
            T2_FM(ga, j0);
            if (j0 + 16 < C_) { T2_LD(ga, j0 + 16); }
            T2_FM(gb2, j0 + 8);
        }
    }

    // ---- RoPE finalize + fragment-ordered kf/vf writes (formulas verbatim) ----
    const int t = tid & (HD - 1);
    const int nh = tid >> 5;
#pragma unroll
    for (int m = 0; m < 4; ++m) {
        int token = tok0 + m;
        int b = token >> 8, s = token & (S_ - 1);
        int bh = b * NHD + nh;
        float kv = k_s[m * C_ + tid];
        float vv = accV[m];
        float partner = (t < 16) ? -k_s[m * C_ + tid + 16] : k_s[m * C_ + tid - 16];
        float ph = accP[m];
        float kr = kv * cosf(ph) + partner * sinf(ph);
        kf[(((size_t)bh * 16 + (s >> 4)) * 64 + (t >> 3) * 16 + (s & 15)) * 8 + (t & 7)] = f2bf(kr);
        vf[((((size_t)bh * 8 + (s >> 5)) * 2 + (t >> 4)) * 64 + ((s >> 3) & 3) * 16 + (t & 15)) * 8 + (s & 7)] = f2bf(vv);
    }
}

// 3D rope freq (verified R3/R4/R6)
__device__ __forceinline__ float freq3d(int t, int n){
    int d = n >> 10, h = (n >> 5) & 31, w = n & 31;
    float pos, ex;
    if (t < 10)      { pos = (float)d; ex = (float)(2 * (t % 5)) * 0.1f; }
    else if (t < 20) { pos = (float)h; ex = (float)(2 * ((t - 10) % 5)) * 0.1f; }
    else             { pos = (float)w; ex = (float)(2 * ((t - 20) % 6)) * (1.0f / 12.0f); }
    return pos * expf(-ex * 9.210340371976184f);
}

// ---------------------------------------------------------------------------
// FUSED: A-transpose + qproj + RoPE + attention + oproj (R3 structure).
// R5 changes vs R3:
//  - A staged in four 16KB quarters [64c][64n] f32, double-buffered through
//    the 2 slots (gather of quarter q overlaps DMA of quarter q+1)
//  - XOR key changed c&15 -> ((c_loc>>3)<<1)&15: gather pos-low3 now spans
//    all 8 values across the wave (qd*2 term) -> 32 banks, 2 lanes/bank
//    (free) instead of 4-way conflict. Same key at stage & gather -> data
//    placement self-consistent; element math unchanged:
//    af[cc][j] = bf16(fv[b][cc*32+qd*8+j][n0+wv*16+l15]).
// ---------------------------------------------------------------------------
__global__ __launch_bounds__(256, 4) void fused_visual(
    const float* __restrict__ fv, const short* __restrict__ wqf,
    const float* __restrict__ q_b, const short* __restrict__ kf,
    const short* __restrict__ vf, const short* __restrict__ wof,
    const float* __restrict__ o_b, float* __restrict__ out)
{
    __shared__ __align__(16) short Stg[16384];      // 2 slots x 8192 shorts (16KB each)
    __shared__ __align__(16) short Pb[4 * 16 * 64]; // 8 KB (P; Ot aliases)
    const int tid = threadIdx.x;
    const int lane = tid & 63;
    const int l15 = tid & 15, qd = (tid >> 4) & 3, wv = tid >> 6;
    const int n0 = blockIdx.x * 64;
    const int b = blockIdx.y;
    const f32x4 z4 = {0.f, 0.f, 0.f, 0.f};
    const float scale = 0.17677669529663687f;  // 32^-0.5, folded into Q

    short* slot0 = Stg;
    short* slot1 = Stg + 8192;

    // ---------------- A-operand: fv -> af[8], 4 pipelined quarters ---------
    bf16x8 af[8];
    {
        const float* fvb = fv + (size_t)(b * C_) * N_ + n0;
        // stage quarter qq (64 c-rows x 64 n f32 = 16KB) into slot s
        auto stage_q = [&](int qq, short* s) {
#pragma unroll
            for (int r = 0; r < 4; ++r) {
                int slot = r * 256 + tid;                 // granule 0..1023
                int c_loc = slot >> 4;                    // 0..63
                int key = ((c_loc >> 3) << 1) & 15;
                int u = (slot & 15) ^ key;                // pre-swizzled n-chunk
                async_cp16(fvb + (size_t)(qq * 64 + c_loc) * N_ + u * 4,
                           s + (r * 256 + (tid & 192)) * 8);
            }
        };
        // gather quarter qq's two cc-blocks from slot s
        auto gather_q = [&](int qq, const short* s) {
            const float* Tsf = (const float*)s;
#pragma unroll
            for (int cc2 = 0; cc2 < 2; ++cc2) {
                bf16x8 a;
#pragma unroll
                for (int j = 0; j < 8; ++j) {
                    int c_loc = cc2 * 32 + qd * 8 + j;    // 0..63
                    int key = ((c_loc >> 3) << 1) & 15;
                    int pos = (wv * 4 + (l15 >> 2)) ^ key;
                    a[j] = f2bf(Tsf[c_loc * 64 + pos * 4 + (l15 & 3)]);
                }
                af[qq * 2 + cc2] = a;
            }
        };
        stage_q(0, slot0);
        stage_q(1, slot1);
        __syncthreads();            // q0,q1 landed
        gather_q(0, slot0);
        __syncthreads();            // all waves done with slot0
        stage_q(2, slot0);
        gather_q(1, slot1);
        __syncthreads();            // q2 landed; all done with slot1
        stage_q(3, slot1);
        gather_q(2, slot0);
        __syncthreads();            // q3 landed; all done with slot0
        gather_q(3, slot1);
        // slot0 free now; slot1 reads done before next barrier (ring start)
    }

    // ---------------- qproj (staged-ring wq; verified R2/R3) ---------------
    f32x4 acc[16];
#pragma unroll
    for (int i = 0; i < 16; ++i) acc[i] = z4;

    stage_tile(wqf, slot0, tid);     // wq tile 0

#pragma unroll
    for (int ntp = 0; ntp < 8; ++ntp) {
        __syncthreads();             // wq tile ntp landed (+ q3 gathers done at ntp=0)
        if (ntp < 7) stage_tile(wqf + (ntp + 1) * 8192, (ntp & 1) ? slot0 : slot1, tid);
        const short* sb = (ntp & 1) ? slot1 : slot0;
#pragma unroll
        for (int cc = 0; cc < 8; ++cc)
#pragma unroll
            for (int ntl = 0; ntl < 2; ++ntl) {
                bf16x8 bq = *(const bf16x8*)&sb[((ntl * 8 + cc) * 64 + lane) * 8];
                acc[ntp * 2 + ntl] = MFMA16(af[cc], bq, acc[ntp * 2 + ntl]);
            }
    }
    __syncthreads();   // all waves done with last wq tile; Stg reusable as scratch

    // ---------------- RoPE -> wave-private scratch, aqh[] to regs ----------
    short* Qsc = Stg + wv * 4096;    // 8KB per wave (16 rows x 256 shorts)
#pragma unroll
    for (int r = 0; r < 4; ++r) {
        int lr = qd * 4 + r;                  // local row
        int n = n0 + wv * 16 + lr;
        int key = lr & 7;
        float f1 = freq3d(l15, n), f2 = freq3d(l15 + 16, n);
        float c1 = cosf(f1), s1 = sinf(f1), c2 = cosf(f2), s2 = sinf(f2);
#pragma unroll
        for (int hh = 0; hh < 8; ++hh) {
            float x1 = acc[2 * hh][r]     + q_b[hh * 32 + l15];
            float x2 = acc[2 * hh + 1][r] + q_b[hh * 32 + 16 + l15];
            int cb1 = (hh * 4 + (l15 >> 3)) ^ key;
            int cb2 = (hh * 4 + 2 + (l15 >> 3)) ^ key;
            Qsc[lr * 256 + cb1 * 8 + (l15 & 7)] = f2bf((x1 * c1 - x2 * s1) * scale);
            Qsc[lr * 256 + cb2 * 8 + (l15 & 7)] = f2bf((x2 * c2 + x1 * s2) * scale);
        }
    }
    // per-wave in-order DS: own writes visible to own reads without barrier
    bf16x8 aqh[8];
#pragma unroll
    for (int h = 0; h < 8; ++h)
        aqh[h] = *(const bf16x8*)&Qsc[l15 * 256 + ((h * 4 + qd) ^ (l15 & 7)) * 8];

    __syncthreads();   // all waves done with scratch -> slot0 free for K(0)
    stage_tile(kf + (size_t)(b * NHD) * 8192, slot0, tid);

    // ---------------- attention + accumulated oproj ----------------
    f32x4 acc_co[16];
#pragma unroll
    for (int i = 0; i < 16; ++i) acc_co[i] = z4;
    short* Pw = Pb + wv * 16 * 64;
    short* Ow = Pw;   // alias (per-wave in-order DS makes this safe)

#pragma unroll
    for (int h = 0; h < 8; ++h) {
        const int bh = b * NHD + h;
        __syncthreads();                                   // K(h) landed
        stage_tile(wof + (size_t)h * 8192, slot1, tid);    // WO(h): consumed after mid barrier

        const short* vbase = vf + (size_t)bh * 8192;

        float tsum[4] = {0.f, 0.f, 0.f, 0.f};
        f32x4 o0 = z4, o1 = z4;

#pragma unroll
        for (int qt = 0; qt < 4; ++qt) {
            f32x4 sc[4];
#pragma unroll
            for (int s4 = 0; s4 < 4; ++s4) {
                bf16x8 bk = *(const bf16x8*)&slot0[(qt * 4 + s4) * 512 + lane * 8];
                sc[s4] = MFMA16(aqh[h], bk, z4);
            }
#pragma unroll
            for (int s4 = 0; s4 < 4; ++s4)
#pragma unroll
                for (int r = 0; r < 4; ++r) {
                    sc[s4][r] = __expf(sc[s4][r]);
                    tsum[r] += sc[s4][r];
                }
#pragma unroll
            for (int s4 = 0; s4 < 4; ++s4)
#pragma unroll
                for (int r = 0; r < 4; ++r) {
                    int row = qd * 4 + r;
                    Pw[row * 64 + ((s4 * 2 + (l15 >> 3)) ^ (row & 7)) * 8 + (l15 & 7)] = f2bf(sc[s4][r]);
                }
#pragma unroll
            for (int ktl = 0; ktl < 2; ++ktl) {
                bf16x8 pa = *(const bf16x8*)&Pw[l15 * 64 + ((ktl * 4 + qd) ^ (l15 & 7)) * 8];
                int kt = qt * 2 + ktl;
                bf16x8 v0 = *(const bf16x8*)&vbase[(kt * 2 + 0) * 512 + lane * 8];
                bf16x8 v1 = *(const bf16x8*)&vbase[(kt * 2 + 1) * 512 + lane * 8];
                o0 = MFMA16(pa, v0, o0);
                o1 = MFMA16(pa, v1, o1);
            }
        }
        float il[4];
#pragma unroll
        for (int r = 0; r < 4; ++r) {
            float t = tsum[r];
            t += __shfl_xor(t, 1); t += __shfl_xor(t, 2);
            t += __shfl_xor(t, 4); t += __shfl_xor(t, 8);
            il[r] = 1.f / t;
        }
        // O -> Ot (aliased in Pw), key = row&3
#pragma unroll
        for (int r = 0; r < 4; ++r) {
            int row = qd * 4 + r;
            int key = row & 3;
            Ow[row * 32 + (((l15 >> 3) ^ key) & 3) * 8 + (l15 & 7)]       = f2bf(o0[r] * il[r]);
            Ow[row * 32 + (((2 + (l15 >> 3)) ^ key) & 3) * 8 + (l15 & 7)] = f2bf(o1[r] * il[r]);
        }

        __syncthreads();   // WO(h) landed; all waves done reading K(h) -> slot0 free
        if (h < 7)
            stage_tile(kf + (size_t)(bh + 1) * 8192, slot0, tid);  // covered by oproj

        // oproj from slot1 (LDS); Ow is wave-private Pb, untouched by staging
        bf16x8 bo = *(const bf16x8*)&Ow[l15 * 32 + ((qd ^ (l15 & 3)) & 3) * 8];
#pragma unroll
        for (int mt = 0; mt < 16; ++mt) {
            bf16x8 ao = *(const bf16x8*)&slot1[mt * 512 + lane * 8];
            acc_co[mt] = MFMA16(ao, bo, acc_co[mt]);
        }
    }

    // ---------------- epilogue: rows = co, cols = n -> coalesced stores ----
#pragma unroll
    for (int mt = 0; mt < 16; ++mt)
#pragma unroll
        for (int r = 0; r < 4; ++r) {
            int co = mt * 16 + qd * 4 + r;
            out[(size_t)(b * C_ + co) * N_ + n0 + wv * 16 + l15] = acc_co[mt][r] + o_b[co];
        }
}

// ---------------------------------------------------------------------------
extern "C" void kernel_launch(void* const* d_in, const int* in_sizes, int n_in,
                              void* d_out, int out_size, void* d_ws, size_t ws_size,
                              hipStream_t stream) {
    (void)in_sizes; (void)n_in; (void)out_size; (void)ws_size;
    const float* fv   = (const float*)d_in[0];
    const float* text = (const float*)d_in[1];
    const float* q_w  = (const float*)d_in[2];
    const float* q_b  = (const float*)d_in[3];
    const float* k_w  = (const float*)d_in[4];
    const float* k_b  = (const float*)d_in[5];
    const float* v_w  = (const float*)d_in[6];
    const float* v_b  = (const float*)d_in[7];
    const float* o_w  = (const float*)d_in[8];
    const float* o_b  = (const float*)d_in[9];
    const float* m1_w = (const float*)d_in[10];
    const float* m1_b = (const float*)d_in[11];
    const float* m2_w = (const float*)d_in[12];
    const float* m2_b = (const float*)d_in[13];
    float* out = (float*)d_out;

    short* wsS  = (short*)d_ws;
    short* kf   = wsS;                      // 131072 shorts
    short* vf   = wsS + 131072;             // 131072
    short* wqf  = wsS + 262144;             // 65536
    short* wof  = wsS + 327680;             // 65536

    hipLaunchKernelGGL(text_all, dim3(192), dim3(256), 0, stream,
                       text, k_w, k_b, v_w, v_b, m1_w, m1_b, m2_w, m2_b,
                       q_w, o_w, kf, vf, wqf, wof);
    hipLaunchKernelGGL(fused_visual, dim3(512, 2), dim3(256), 0, stream,
                       fv, wqf, q_b, kf, vf, wof, o_b, out);
}

// Round 7
// 279.586 us; speedup vs baseline: 1.1054x; 1.0916x over previous
//
#include <hip/hip_runtime.h>
#include <hip/hip_bf16.h>

#define NHD 8
#define HD  32
#define C_  256
#define TD_ 512
#define S_  256
#define N_  32768   // D*H*W
#define B_  2

typedef short bf16x8 __attribute__((ext_vector_type(8)));
typedef short bf16x4 __attribute__((ext_vector_type(4)));
typedef float f32x4  __attribute__((ext_vector_type(4)));

#define MFMA16(a,b,c) __builtin_amdgcn_mfma_f32_16x16x32_bf16(a,b,c,0,0,0)

__device__ __forceinline__ short f2bf(float f){
    __hip_bfloat16 h = __float2bfloat16(f);
    return *reinterpret_cast<short*>(&h);
}

// ---------------------------------------------------------------------------
// async global->LDS staging (16B/lane, linear dest; verified R1/R2/R3).
// ---------------------------------------------------------------------------
typedef __attribute__((address_space(3))) unsigned int lds_u32;
typedef const __attribute__((address_space(1))) unsigned int glb_u32;

__device__ __forceinline__ void async_cp16(const void* g, void* l){
    __builtin_amdgcn_global_load_lds(
        (glb_u32*)(unsigned long long)g,
        (lds_u32*)(unsigned int)(unsigned long long)l,
        16, 0, 0);
}

// stage one 16 KB verbatim tile (8192 shorts): 4 rounds x 256 thr x 16B
__device__ __forceinline__ void stage_tile(const short* __restrict__ g, short* l, int tid){
    const int wvb = tid & 192;            // (tid>>6)<<6 : wave-uniform
#pragma unroll
    for (int r = 0; r < 4; ++r)
        async_cp16(g + (r * 256 + tid) * 8, l + (r * 256 + wvb) * 8);
}

// ---------------------------------------------------------------------------
// text_all (verbatim from R6, measured good): k/v/m1 GEMM (+gelu) AND m2
// phase GEMM AND RoPE finalize, one kernel. 128 GEMM blocks x 4 tokens.
// Blocks 128..191: prep_wf fold (body verbatim, verified).
// ---------------------------------------------------------------------------
#define T1_LD(K,V,M,j0) _Pragma("unroll") for(int i=0;i<8;++i){ \
    K[i]=kp[(j0+i)*C_]; V[i]=vp[(j0+i)*C_]; M[i]=mp[(j0+i)*C_]; }
#define T1_FM(K,V,M,j0) _Pragma("unroll") for(int i=0;i<8;++i){ \
    _Pragma("unroll") for(int m=0;m<4;++m){ float tv=t_s[m*TD_+j0+i]; \
        accK[m]+=tv*K[i]; accV[m]+=tv*V[i]; accH[m]+=tv*M[i]; } }
#define T2_LD(G, j0) _Pragma("unroll") for (int i = 0; i < 8; ++i) G[i] = m2p[(j0 + i) * C_];
#define T2_FM(G, j0) _Pragma("unroll") for (int i = 0; i < 8; ++i) { \
    _Pragma("unroll") for (int m = 0; m < 4; ++m) accP[m] += h_s[m * C_ + j0 + i] * G[i]; }

__global__ __launch_bounds__(256) void text_all(
    const float* __restrict__ text,
    const float* __restrict__ k_w, const float* __restrict__ k_b,
    const float* __restrict__ v_w, const float* __restrict__ v_b,
    const float* __restrict__ m1_w, const float* __restrict__ m1_b,
    const float* __restrict__ m2_w, const float* __restrict__ m2_b,
    const float* __restrict__ qw, const float* __restrict__ ow,
    short* __restrict__ kf, short* __restrict__ vf,
    short* __restrict__ wqf, short* __restrict__ wof)
{
    const int tid = threadIdx.x;

    if (blockIdx.x >= 128) {
        // ---- prep_wf fold (verbatim, verified) ----
        int gid = (blockIdx.x - 128) * 256 + tid;   // 0..16383
        int m = gid >> 13;
        int rest = gid & 8191;
        const float* src = m ? ow : qw;
        short* dst = m ? wof : wqf;
        int lane = rest & 63;
        int l15 = lane & 15, qd = lane >> 4;
        int cbase, co;
        if (m == 0) { int nt = rest >> 9, cc = (rest >> 6) & 7; cbase = cc * 32 + qd * 8; co = nt * 16 + l15; }
        else        { int hm = rest >> 6; cbase = (hm >> 4) * 32 + qd * 8; co = (hm & 15) * 16 + l15; }
        bf16x8 r;
#pragma unroll
        for (int j = 0; j < 8; ++j) r[j] = f2bf(src[(size_t)(cbase + j) * 256 + co]);
        *(bf16x8*)&dst[(size_t)rest * 8] = r;
        return;
    }

    __shared__ float t_s[4 * TD_];    // 8 KB
    __shared__ float h_s[4 * C_];     // 4 KB
    __shared__ float k_s[4 * C_];     // 4 KB
    const int tok0 = blockIdx.x * 4;
#pragma unroll
    for (int i = 0; i < 2; ++i) {
        int idx = i * 256 + tid;      // 0..511 float4 units
        *(float4*)&t_s[idx * 4] = *(const float4*)&text[(size_t)tok0 * TD_ + idx * 4];
    }
    __syncthreads();

    float accK[4], accV[4], accH[4];
#pragma unroll
    for (int m = 0; m < 4; ++m) { accK[m] = k_b[tid]; accV[m] = v_b[tid]; accH[m] = m1_b[tid]; }
    const float* kp = k_w + tid;
    const float* vp = v_w + tid;
    const float* mp = m1_w + tid;

    {
        float ka[8], va[8], ma[8], kb2[8], vb2[8], mb2[8];
        T1_LD(ka, va, ma, 0);
#pragma unroll 1
        for (int j0 = 0; j0 < TD_; j0 += 16) {
            T1_LD(kb2, vb2, mb2, j0 + 8);
            T1_FM(ka, va, ma, j0);
            if (j0 + 16 < TD_) { T1_LD(ka, va, ma, j0 + 16); }
            T1_FM(kb2, vb2, mb2, j0 + 8);
        }
    }

#pragma unroll
    for (int m = 0; m < 4; ++m) {
        k_s[m * C_ + tid] = accK[m];
        float hv = accH[m];
        h_s[m * C_ + tid] = 0.5f * hv * (1.0f + erff(hv * 0.70710678118654752f));
    }
    __syncthreads();

    // ---- m2 phase GEMM (ascending j, init m2_b -> bit-identical) ----
    float accP[4];
#pragma unroll
    for (int m = 0; m < 4; ++m) accP[m] = m2_b[tid];
    const float* m2p = m2_w + tid;
    {
        float ga[8], gb2[8];
        T2_LD(ga, 0);
#pragma unroll 1
        for (int j0 = 0; j0 < C_; j0 += 16) {
            T2_LD(gb2, j0 + 8);
            T2_FM(ga, j0);
            if (j0 + 16 < C_) { T2_LD(ga, j0 + 16); }
            T2_FM(gb2, j0 + 8);
        }
    }

    // ---- RoPE finalize + fragment-ordered kf/vf writes (formulas verbatim) ----
    const int t = tid & (HD - 1);
    const int nh = tid >> 5;
#pragma unroll
    for (int m = 0; m < 4; ++m) {
        int token = tok0 + m;
        int b = token >> 8, s = token & (S_ - 1);
        int bh = b * NHD + nh;
        float kv = k_s[m * C_ + tid];
        float vv = accV[m];
        float partner = (t < 16) ? -k_s[m * C_ + tid + 16] : k_s[m * C_ + tid - 16];
        float ph = accP[m];
        float kr = kv * cosf(ph) + partner * sinf(ph);
        kf[(((size_t)bh * 16 + (s >> 4)) * 64 + (t >> 3) * 16 + (s & 15)) * 8 + (t & 7)] = f2bf(kr);
        vf[((((size_t)bh * 8 + (s >> 5)) * 2 + (t >> 4)) * 64 + ((s >> 3) & 3) * 16 + (t & 15)) * 8 + (s & 7)] = f2bf(vv);
    }
}

// 3D rope freq (verified R3/R4/R6)
__device__ __forceinline__ float freq3d(int t, int n){
    int d = n >> 10, h = (n >> 5) & 31, w = n & 31;
    float pos, ex;
    if (t < 10)      { pos = (float)d; ex = (float)(2 * (t % 5)) * 0.1f; }
    else if (t < 20) { pos = (float)h; ex = (float)(2 * ((t - 10) % 5)) * 0.1f; }
    else             { pos = (float)w; ex = (float)(2 * ((t - 20) % 6)) * (1.0f / 12.0f); }
    return pos * expf(-ex * 9.210340371976184f);
}

// ---------------------------------------------------------------------------
// FUSED (verbatim from R3, measured 132 us): A-transpose + qproj + RoPE +
// attention + oproj. A staged as two 32KB f32 c-halves into the full Stg via
// global_load_lds with pre-swizzled source (u' = u ^ (c_loc&15)); per-wave
// scalar f32 gathers -> af[8]. Everything else = verified R2 ring structure.
// ---------------------------------------------------------------------------
__global__ __launch_bounds__(256, 4) void fused_visual(
    const float* __restrict__ fv, const short* __restrict__ wqf,
    const float* __restrict__ q_b, const short* __restrict__ kf,
    const short* __restrict__ vf, const short* __restrict__ wof,
    const float* __restrict__ o_b, float* __restrict__ out)
{
    __shared__ __align__(16) short Stg[16384];      // 2 slots x 8192 shorts (16KB each)
    __shared__ __align__(16) short Pb[4 * 16 * 64]; // 8 KB (P; Ot aliases)
    const int tid = threadIdx.x;
    const int lane = tid & 63;
    const int l15 = tid & 15, qd = (tid >> 4) & 3, wv = tid >> 6;
    const int n0 = blockIdx.x * 64;
    const int b = blockIdx.y;
    const f32x4 z4 = {0.f, 0.f, 0.f, 0.f};
    const float scale = 0.17677669529663687f;  // 32^-0.5, folded into Q

    short* slot0 = Stg;
    short* slot1 = Stg + 8192;

    // ---------------- A-operand: fv -> af[8] (2 c-halves x 32KB) ----------
    bf16x8 af[8];
    const float* Tsf = (const float*)Stg;
#pragma unroll
    for (int ch = 0; ch < 2; ++ch) {
        // stage: 128 c-rows x 64 n f32; LDS linear, source pre-swizzled
#pragma unroll
        for (int r = 0; r < 8; ++r) {
            int slot = r * 256 + tid;                 // 0..2047
            int c_loc = slot >> 4;
            int u = (slot & 15) ^ (c_loc & 15);       // pre-swizzled n-chunk
            async_cp16(fv + (size_t)(b * C_ + ch * 128 + c_loc) * N_ + n0 + u * 4,
                       Stg + (r * 256 + (tid & 192)) * 8);
        }
        __syncthreads();   // staged half landed (vmcnt(0) before barrier)
#pragma unroll
        for (int cc2 = 0; cc2 < 4; ++cc2) {
            bf16x8 a;
#pragma unroll
            for (int j = 0; j < 8; ++j) {
                int c_loc = cc2 * 32 + qd * 8 + j;    // 0..127
                int u = (wv * 4 + (l15 >> 2)) ^ (c_loc & 15);
                float x = Tsf[c_loc * 64 + u * 4 + (l15 & 3)];
                a[j] = f2bf(x);
            }
            af[ch * 4 + cc2] = a;
        }
        __syncthreads();   // all gathers done before Stg is overwritten
    }

    // ---------------- qproj (staged-ring wq; verified R2) ----------------
    f32x4 acc[16];
#pragma unroll
    for (int i = 0; i < 16; ++i) acc[i] = z4;

    stage_tile(wqf, slot0, tid);     // wq tile 0

#pragma unroll
    for (int ntp = 0; ntp < 8; ++ntp) {
        __syncthreads();             // wq tile ntp landed
        if (ntp < 7) stage_tile(wqf + (ntp + 1) * 8192, (ntp & 1) ? slot0 : slot1, tid);
        const short* sb = (ntp & 1) ? slot1 : slot0;
#pragma unroll
        for (int cc = 0; cc < 8; ++cc)
#pragma unroll
            for (int ntl = 0; ntl < 2; ++ntl) {
                bf16x8 bq = *(const bf16x8*)&sb[((ntl * 8 + cc) * 64 + lane) * 8];
                acc[ntp * 2 + ntl] = MFMA16(af[cc], bq, acc[ntp * 2 + ntl]);
            }
    }
    __syncthreads();   // all waves done with last wq tile; Stg reusable as scratch

    // ---------------- RoPE -> wave-private scratch, aqh[] to regs ----------
    short* Qsc = Stg + wv * 4096;    // 8KB per wave (16 rows x 256 shorts)
#pragma unroll
    for (int r = 0; r < 4; ++r) {
        int lr = qd * 4 + r;                  // local row
        int n = n0 + wv * 16 + lr;
        int key = lr & 7;
        float f1 = freq3d(l15, n), f2 = freq3d(l15 + 16, n);
        float c1 = cosf(f1), s1 = sinf(f1), c2 = cosf(f2), s2 = sinf(f2);
#pragma unroll
        for (int hh = 0; hh < 8; ++hh) {
            float x1 = acc[2 * hh][r]     + q_b[hh * 32 + l15];
            float x2 = acc[2 * hh + 1][r] + q_b[hh * 32 + 16 + l15];
            int cb1 = (hh * 4 + (l15 >> 3)) ^ key;
            int cb2 = (hh * 4 + 2 + (l15 >> 3)) ^ key;
            Qsc[lr * 256 + cb1 * 8 + (l15 & 7)] = f2bf((x1 * c1 - x2 * s1) * scale);
            Qsc[lr * 256 + cb2 * 8 + (l15 & 7)] = f2bf((x2 * c2 + x1 * s2) * scale);
        }
    }
    // per-wave in-order DS: own writes visible to own reads without barrier
    bf16x8 aqh[8];
#pragma unroll
    for (int h = 0; h < 8; ++h)
        aqh[h] = *(const bf16x8*)&Qsc[l15 * 256 + ((h * 4 + qd) ^ (l15 & 7)) * 8];

    __syncthreads();   // all waves done with scratch -> slot0 free for K(0)
    stage_tile(kf + (size_t)(b * NHD) * 8192, slot0, tid);

    // ---------------- attention + accumulated oproj ----------------
    f32x4 acc_co[16];
#pragma unroll
    for (int i = 0; i < 16; ++i) acc_co[i] = z4;
    short* Pw = Pb + wv * 16 * 64;
    short* Ow = Pw;   // alias (per-wave in-order DS makes this safe)

#pragma unroll
    for (int h = 0; h < 8; ++h) {
        const int bh = b * NHD + h;
        __syncthreads();                                   // K(h) landed
        stage_tile(wof + (size_t)h * 8192, slot1, tid);    // WO(h): consumed after mid barrier

        const short* vbase = vf + (size_t)bh * 8192;

        float tsum[4] = {0.f, 0.f, 0.f, 0.f};
        f32x4 o0 = z4, o1 = z4;

#pragma unroll
        for (int qt = 0; qt < 4; ++qt) {
            f32x4 sc[4];
#pragma unroll
            for (int s4 = 0; s4 < 4; ++s4) {
                bf16x8 bk = *(const bf16x8*)&slot0[(qt * 4 + s4) * 512 + lane * 8];
                sc[s4] = MFMA16(aqh[h], bk, z4);
            }
#pragma unroll
            for (int s4 = 0; s4 < 4; ++s4)
#pragma unroll
                for (int r = 0; r < 4; ++r) {
                    sc[s4][r] = __expf(sc[s4][r]);
                    tsum[r] += sc[s4][r];
                }
#pragma unroll
            for (int s4 = 0; s4 < 4; ++s4)
#pragma unroll
                for (int r = 0; r < 4; ++r) {
                    int row = qd * 4 + r;
                    Pw[row * 64 + ((s4 * 2 + (l15 >> 3)) ^ (row & 7)) * 8 + (l15 & 7)] = f2bf(sc[s4][r]);
                }
#pragma unroll
            for (int ktl = 0; ktl < 2; ++ktl) {
                bf16x8 pa = *(const bf16x8*)&Pw[l15 * 64 + ((ktl * 4 + qd) ^ (l15 & 7)) * 8];
                int kt = qt * 2 + ktl;
                bf16x8 v0 = *(const bf16x8*)&vbase[(kt * 2 + 0) * 512 + lane * 8];
                bf16x8 v1 = *(const bf16x8*)&vbase[(kt * 2 + 1) * 512 + lane * 8];
                o0 = MFMA16(pa, v0, o0);
                o1 = MFMA16(pa, v1, o1);
            }
        }
        float il[4];
#pragma unroll
        for (int r = 0; r < 4; ++r) {
            float t = tsum[r];
            t += __shfl_xor(t, 1); t += __shfl_xor(t, 2);
            t += __shfl_xor(t, 4); t += __shfl_xor(t, 8);
            il[r] = 1.f / t;
        }
        // O -> Ot (aliased in Pw), key = row&3
#pragma unroll
        for (int r = 0; r < 4; ++r) {
            int row = qd * 4 + r;
            int key = row & 3;
            Ow[row * 32 + (((l15 >> 3) ^ key) & 3) * 8 + (l15 & 7)]       = f2bf(o0[r] * il[r]);
            Ow[row * 32 + (((2 + (l15 >> 3)) ^ key) & 3) * 8 + (l15 & 7)] = f2bf(o1[r] * il[r]);
        }

        __syncthreads();   // WO(h) landed; all waves done reading K(h) -> slot0 free
        if (h < 7)
            stage_tile(kf + (size_t)(bh + 1) * 8192, slot0, tid);  // covered by oproj

        // oproj from slot1 (LDS); Ow is wave-private Pb, untouched by staging
        bf16x8 bo = *(const bf16x8*)&Ow[l15 * 32 + ((qd ^ (l15 & 3)) & 3) * 8];
#pragma unroll
        for (int mt = 0; mt < 16; ++mt) {
            bf16x8 ao = *(const bf16x8*)&slot1[mt * 512 + lane * 8];
            acc_co[mt] = MFMA16(ao, bo, acc_co[mt]);
        }
    }

    // ---------------- epilogue: rows = co, cols = n -> coalesced stores ----
#pragma unroll
    for (int mt = 0; mt < 16; ++mt)
#pragma unroll
        for (int r = 0; r < 4; ++r) {
            int co = mt * 16 + qd * 4 + r;
            out[(size_t)(b * C_ + co) * N_ + n0 + wv * 16 + l15] = acc_co[mt][r] + o_b[co];
        }
}

// ---------------------------------------------------------------------------
extern "C" void kernel_launch(void* const* d_in, const int* in_sizes, int n_in,
                              void* d_out, int out_size, void* d_ws, size_t ws_size,
                              hipStream_t stream) {
    (void)in_sizes; (void)n_in; (void)out_size; (void)ws_size;
    const float* fv   = (const float*)d_in[0];
    const float* text = (const float*)d_in[1];
    const float* q_w  = (const float*)d_in[2];
    const float* q_b  = (const float*)d_in[3];
    const float* k_w  = (const float*)d_in[4];
    const float* k_b  = (const float*)d_in[5];
    const float* v_w  = (const float*)d_in[6];
    const float* v_b  = (const float*)d_in[7];
    const float* o_w  = (const float*)d_in[8];
    const float* o_b  = (const float*)d_in[9];
    const float* m1_w = (const float*)d_in[10];
    const float* m1_b = (const float*)d_in[11];
    const float* m2_w = (const float*)d_in[12];
    const float* m2_b = (const float*)d_in[13];
    float* out = (float*)d_out;

    short* wsS  = (short*)d_ws;
    short* kf   = wsS;                      // 131072 shorts
    short* vf   = wsS + 131072;             // 131072
    short* wqf  = wsS + 262144;             // 65536
    short* wof  = wsS + 327680;             // 65536

    hipLaunchKernelGGL(text_all, dim3(192), dim3(256), 0, stream,
                       text, k_w, k_b, v_w, v_b, m1_w, m1_b, m2_w, m2_b,
                       q_w, o_w, kf, vf, wqf, wof);
    hipLaunchKernelGGL(fused_visual, dim3(512, 2), dim3(256), 0, stream,
                       fv, wqf, q_b, kf, vf, wof, o_b, out);
}